// Round 1
// baseline (140.892 us; speedup 1.0000x reference)
//
#include <hip/hip_runtime.h>
#include <hip/hip_bf16.h>
#include <stdint.h>

// Problem constants
#define BATCH 8
#define CH    256     // C
#define CQK   32      // query/key channels
#define NPIX  4096    // H*W
#define MALL  320     // CQK + CQK + CH combined projection rows

using bfrag = __attribute__((ext_vector_type(8))) short;     // 8 bf16 = 4 VGPR (MFMA A/B)
using f32x4 = __attribute__((ext_vector_type(4))) float;     // MFMA C/D
using u32x2 = __attribute__((ext_vector_type(2))) unsigned int;

#define MFMA16(A, B, C) __builtin_amdgcn_mfma_f32_16x16x32_bf16(A, B, C, 0, 0, 0)

__device__ __forceinline__ unsigned short f2bf(float f) {
  union { float f; unsigned int u; } v; v.f = f;
  unsigned int r = v.u + 0x7FFFu + ((v.u >> 16) & 1u);   // RNE
  return (unsigned short)(r >> 16);
}

__device__ __forceinline__ void gload_lds16(const void* g, void* l) {
  __builtin_amdgcn_global_load_lds(
      (const __attribute__((address_space(1))) unsigned int*)g,
      (__attribute__((address_space(3))) unsigned int*)l, 16, 0, 0);
}

// ---------------- kernel 0: cast weights to bf16 ----------------
__global__ void prep_kernel(const float* __restrict__ Wf, const float* __restrict__ Wg,
                            const float* __restrict__ Wh, const float* __restrict__ Wv,
                            unsigned short* __restrict__ Wall, unsigned short* __restrict__ Wvb) {
  int i = blockIdx.x * 256 + threadIdx.x;
  if (i < MALL * CH) {
    int m = i >> 8, c = i & 255;
    float v = (m < CQK)     ? Wf[m * CH + c]
            : (m < 2 * CQK) ? Wg[(m - CQK) * CH + c]
                            : Wh[(m - 2 * CQK) * CH + c];
    Wall[i] = f2bf(v);
  }
  if (i < CH * CH) Wvb[i] = f2bf(Wv[i]);
}

// ---------------- kernel 1: f,g,h projections (MFMA GEMM) ----------------
// out[m][n] = sum_c Wall[m][c] * x[b][c][n]  for one 64-pixel tile; M=320, K=256.
// Writes Q,K as [b][n][32] bf16 (row-major per pixel) and V as [b][c][n] bf16.
__global__ __launch_bounds__(256, 2)
void proj_kernel(const float* __restrict__ x, const unsigned short* __restrict__ Wall,
                 const float* __restrict__ bfb, const float* __restrict__ bgb,
                 const float* __restrict__ bhb,
                 unsigned short* __restrict__ Qo, unsigned short* __restrict__ Ko,
                 unsigned short* __restrict__ Vo) {
  __shared__ char xT[64 * 512];  // xT[n][c] bf16, rows 512B, 16B-chunk XOR (n&7)
  const int b  = blockIdx.x & 7;
  const int n0 = (blockIdx.x >> 3) * 64;
  const int tid = threadIdx.x;
  const int lane = tid & 63, wave = tid >> 6;
  const int lr = lane & 15, g = lane >> 4;

  // load + transpose x tile (fp32 -> bf16)
  for (int it = 0; it < 16; ++it) {
    int c = it * 16 + wave * 4 + g;
    int nn = lr * 4;
    const float4 v = *(const float4*)(x + (size_t)(b * CH + c) * NPIX + n0 + nn);
    const float* vp = (const float*)&v;
#pragma unroll
    for (int j = 0; j < 4; ++j) {
      int n = nn + j;
      int byteoff = n * 512 + (((c >> 3) ^ (n & 7)) << 4) + ((c & 7) * 2);
      *(unsigned short*)(xT + byteoff) = f2bf(vp[j]);
    }
  }
  __syncthreads();

  f32x4 acc[5][4] = {};
  for (int ks = 0; ks < 8; ++ks) {
    bfrag bfr[4];
#pragma unroll
    for (int nt = 0; nt < 4; ++nt) {
      int n = nt * 16 + lr;
      bfr[nt] = *(const bfrag*)(xT + n * 512 + (((ks * 4 + g) ^ (n & 7)) << 4));
    }
#pragma unroll
    for (int i = 0; i < 5; ++i) {
      int m = (wave + 4 * i) * 16 + lr;
      bfrag afr = *(const bfrag*)(Wall + (size_t)m * CH + ks * 32 + g * 8);
#pragma unroll
      for (int nt = 0; nt < 4; ++nt) acc[i][nt] = MFMA16(afr, bfr[nt], acc[i][nt]);
    }
  }

#pragma unroll
  for (int i = 0; i < 5; ++i) {
    const int mt = wave + 4 * i;
#pragma unroll
    for (int nt = 0; nt < 4; ++nt) {
      const int n = n0 + nt * 16 + lr;
      if (mt < 2) {                     // f -> Q, k index = m
        float v0 = acc[i][nt][0] + bfb[mt * 16 + 4 * g + 0];
        float v1 = acc[i][nt][1] + bfb[mt * 16 + 4 * g + 1];
        float v2 = acc[i][nt][2] + bfb[mt * 16 + 4 * g + 2];
        float v3 = acc[i][nt][3] + bfb[mt * 16 + 4 * g + 3];
        u32x2 pk;
        pk[0] = (unsigned)f2bf(v0) | ((unsigned)f2bf(v1) << 16);
        pk[1] = (unsigned)f2bf(v2) | ((unsigned)f2bf(v3) << 16);
        *(u32x2*)(Qo + (size_t)(b * NPIX + n) * CQK + mt * 16 + 4 * g) = pk;
      } else if (mt < 4) {              // g -> K, k index = m-32
        int k0 = (mt - 2) * 16 + 4 * g;
        float v0 = acc[i][nt][0] + bgb[k0 + 0];
        float v1 = acc[i][nt][1] + bgb[k0 + 1];
        float v2 = acc[i][nt][2] + bgb[k0 + 2];
        float v3 = acc[i][nt][3] + bgb[k0 + 3];
        u32x2 pk;
        pk[0] = (unsigned)f2bf(v0) | ((unsigned)f2bf(v1) << 16);
        pk[1] = (unsigned)f2bf(v2) | ((unsigned)f2bf(v3) << 16);
        *(u32x2*)(Ko + (size_t)(b * NPIX + n) * CQK + k0) = pk;
      } else {                          // h -> V [c][n]
#pragma unroll
        for (int r = 0; r < 4; ++r) {
          int c = mt * 16 + 4 * g + r - 64;
          Vo[(size_t)(b * CH + c) * NPIX + n] = f2bf(acc[i][nt][r] + bhb[c]);
        }
      }
    }
  }
}

// ---------------- kernel 2: flash attention ----------------
// Per block: one batch, 64-query tile. 4 waves. KV tiles of 64, double buffered.
// S^T = mfma(K, Q^T); softmax without max-subtraction (logits are small);
// P re-fragmented through swizzled LDS; PV with c-dim split across waves.
__global__ __launch_bounds__(256, 2)
void attn_kernel(const unsigned short* __restrict__ Qg, const unsigned short* __restrict__ Kg,
                 const unsigned short* __restrict__ Vg, unsigned short* __restrict__ Og) {
  extern __shared__ char smem[];
  char* const Kb0 = smem;                   //  4 KB  K[64][32] bf16, swizzled
  char* const Kb1 = smem + 4096;            //  4 KB
  char* const Vb0 = smem + 8192;            // 32 KB  Vt[256 c][64 j] bf16, swizzled
  char* const Vb1 = smem + 8192 + 32768;    // 32 KB
  char* const Pb  = smem + 8192 + 65536;    //  8 KB  P[64 q][64 j] bf16, swizzled

  const int b  = blockIdx.x & 7;            // batch == XCD pin (blockIdx % 8 round-robin)
  const int q0 = (blockIdx.x >> 3) * 64;
  const int tid = threadIdx.x;
  const int lane = tid & 63, wave = tid >> 6;
  const int lr = lane & 15, g = lane >> 4;

  const unsigned short* Qbase = Qg + (size_t)(b * NPIX + q0) * CQK;
  const unsigned short* Kbase = Kg + (size_t)b * NPIX * CQK;
  const unsigned short* Vbase = Vg + (size_t)b * CH * NPIX;

  // persistent Q fragments (B-operand of S^T): Q[nt*16+lr][8g..8g+7]
  bfrag qf[4];
#pragma unroll
  for (int nt = 0; nt < 4; ++nt)
    qf[nt] = *(const bfrag*)(Qbase + (nt * 16 + lr) * CQK + g * 8);

  // staging source pointers (loop-invariant part)
  const unsigned short* vsrc[8];
#pragma unroll
  for (int i = 0; i < 8; ++i) {
    int ch = i * 256 + tid;
    int c = ch >> 3, G = ch & 7;
    vsrc[i] = Vbase + (size_t)c * NPIX + (G ^ (c & 7)) * 8;
  }
  const unsigned short* ksrc;
  {
    int row = tid >> 2, G = tid & 3;
    ksrc = Kbase + (size_t)row * CQK + (G ^ ((row ^ (row >> 2)) & 3)) * 8;
  }

  auto stage = [&](int t, char* kb, char* vb) {
    gload_lds16(ksrc + (size_t)t * 64 * CQK, kb + wave * 1024);
#pragma unroll
    for (int i = 0; i < 8; ++i)
      gload_lds16(vsrc[i] + (size_t)t * 64, vb + (i * 256 + wave * 64) * 16);
  };

  f32x4 acc[4][4] = {};
  float lp[4] = {0.f, 0.f, 0.f, 0.f};

  const int krow = 16 * wave + lr;
  const int koff = krow * 64 + ((g ^ ((krow ^ (krow >> 2)) & 3)) << 4);
  const int pwG  = 2 * wave + (g >> 1);     // P write chunk index

  stage(0, Kb0, Vb0);
  __syncthreads();

  for (int t = 0; t < 64; ++t) {
    char* kb  = (t & 1) ? Kb1 : Kb0;
    char* vb  = (t & 1) ? Vb1 : Vb0;
    char* kbn = (t & 1) ? Kb0 : Kb1;
    char* vbn = (t & 1) ? Vb0 : Vb1;

    // ---- phase 1: S^T tile (wave's 16-j block x 64 q), exp, P write
    bfrag kf = *(const bfrag*)(kb + koff);
#pragma unroll
    for (int nt = 0; nt < 4; ++nt) {
      f32x4 zero = 0.0f;
      f32x4 st = MFMA16(kf, qf[nt], zero);
      float p0 = __expf(st[0]), p1 = __expf(st[1]);
      float p2 = __expf(st[2]), p3 = __expf(st[3]);
      lp[nt] += (p0 + p1) + (p2 + p3);
      int q = nt * 16 + lr;
      u32x2 pk;
      pk[0] = (unsigned)f2bf(p0) | ((unsigned)f2bf(p1) << 16);
      pk[1] = (unsigned)f2bf(p2) | ((unsigned)f2bf(p3) << 16);
      *(u32x2*)(Pb + q * 128 + ((pwG ^ (q & 7)) << 4) + ((g & 1) << 3)) = pk;
    }
    __syncthreads();

    if (t + 1 < 64) stage(t + 1, kbn, vbn);   // overlaps with PV; drained at tail barrier

    // ---- phase 2: PV, wave owns c-block [64*wave, 64*wave+64)
#pragma unroll
    for (int ks = 0; ks < 2; ++ks) {
      bfrag pf[4], vf[4];
#pragma unroll
      for (int mt = 0; mt < 4; ++mt) {
        int q = mt * 16 + lr;
        pf[mt] = *(const bfrag*)(Pb + q * 128 + (((ks * 4 + g) ^ (q & 7)) << 4));
      }
#pragma unroll
      for (int nt = 0; nt < 4; ++nt) {
        int c = 64 * wave + nt * 16 + lr;
        vf[nt] = *(const bfrag*)(vb + c * 128 + (((ks * 4 + g) ^ (c & 7)) << 4));
      }
#pragma unroll
      for (int mt = 0; mt < 4; ++mt)
#pragma unroll
        for (int nt = 0; nt < 4; ++nt)
          acc[mt][nt] = MFMA16(pf[mt], vf[nt], acc[mt][nt]);
    }
    __syncthreads();
  }

  // ---- epilogue: softmax denominators and normalized store
#pragma unroll
  for (int nt = 0; nt < 4; ++nt) {
    lp[nt] += __shfl_xor(lp[nt], 16);
    lp[nt] += __shfl_xor(lp[nt], 32);
  }
  float* lred = (float*)Pb;   // reuse P region
  if (lane < 16) {
#pragma unroll
    for (int nt = 0; nt < 4; ++nt) lred[wave * 64 + nt * 16 + lr] = lp[nt];
  }
  __syncthreads();
  float inv[4][4];
#pragma unroll
  for (int mt = 0; mt < 4; ++mt)
#pragma unroll
    for (int r = 0; r < 4; ++r) {
      int q = mt * 16 + 4 * g + r;
      float s = lred[q] + lred[64 + q] + lred[128 + q] + lred[192 + q];
      inv[mt][r] = 1.0f / s;
    }
#pragma unroll
  for (int mt = 0; mt < 4; ++mt)
#pragma unroll
    for (int nt = 0; nt < 4; ++nt) {
      int c = 64 * wave + nt * 16 + lr;
#pragma unroll
      for (int r = 0; r < 4; ++r) {
        int q = q0 + mt * 16 + 4 * g + r;
        Og[(size_t)(b * NPIX + q) * CH + c] = f2bf(acc[mt][nt][r] * inv[mt][r]);
      }
    }
}

// ---------------- kernel 3: v-projection + residual ----------------
// out[b][m][n] = x[b][m][n] + gamma * (sum_c Wv[m][c]*attH[b][n][c] + bv[m])
__global__ __launch_bounds__(256, 2)
void vproj_kernel(const unsigned short* __restrict__ attn, const unsigned short* __restrict__ Wvb,
                  const float* __restrict__ bv, const float* __restrict__ x,
                  const float* __restrict__ gamma, float* __restrict__ out) {
  __shared__ char at[64 * 512];   // attH tile [64 n][256 c] bf16, swizzled
  const int b  = blockIdx.x & 7;
  const int n0 = (blockIdx.x >> 3) * 64;
  const int tid = threadIdx.x;
  const int lane = tid & 63, wave = tid >> 6;
  const int lr = lane & 15, g = lane >> 4;

#pragma unroll
  for (int i = 0; i < 8; ++i) {
    int ch = i * 256 + tid;
    int n = ch >> 5, G = ch & 31;
    gload_lds16(attn + (size_t)(b * NPIX + n0 + n) * CH + (G ^ (n & 7)) * 8,
                at + (i * 256 + wave * 64) * 16);
  }
  __syncthreads();

  f32x4 acc[4][4] = {};
  for (int ks = 0; ks < 8; ++ks) {
    bfrag bfr[4];
#pragma unroll
    for (int nt = 0; nt < 4; ++nt) {
      int n = nt * 16 + lr;
      bfr[nt] = *(const bfrag*)(at + n * 512 + (((ks * 4 + g) ^ (n & 7)) << 4));
    }
#pragma unroll
    for (int i = 0; i < 4; ++i) {
      int m = (wave * 4 + i) * 16 + lr;
      bfrag afr = *(const bfrag*)(Wvb + (size_t)m * CH + ks * 32 + g * 8);
#pragma unroll
      for (int nt = 0; nt < 4; ++nt) acc[i][nt] = MFMA16(afr, bfr[nt], acc[i][nt]);
    }
  }
  const float gam = gamma[0];
#pragma unroll
  for (int i = 0; i < 4; ++i)
#pragma unroll
    for (int nt = 0; nt < 4; ++nt) {
      int n = n0 + nt * 16 + lr;
#pragma unroll
      for (int r = 0; r < 4; ++r) {
        int m = (wave * 4 + i) * 16 + 4 * g + r;
        size_t off = (size_t)(b * CH + m) * NPIX + n;
        out[off] = x[off] + gam * (acc[i][nt][r] + bv[m]);
      }
    }
}

extern "C" void kernel_launch(void* const* d_in, const int* in_sizes, int n_in,
                              void* d_out, int out_size, void* d_ws, size_t ws_size,
                              hipStream_t stream) {
  const float* x   = (const float*)d_in[0];
  const float* Wf  = (const float*)d_in[1];
  const float* bfb = (const float*)d_in[2];
  const float* Wg  = (const float*)d_in[3];
  const float* bgb = (const float*)d_in[4];
  const float* Wh  = (const float*)d_in[5];
  const float* bhb = (const float*)d_in[6];
  const float* Wv  = (const float*)d_in[7];
  const float* bv  = (const float*)d_in[8];
  const float* gam = (const float*)d_in[9];
  float* out = (float*)d_out;

  char* ws = (char*)d_ws;
  unsigned short* Wall = (unsigned short*)(ws);              // 163840 B
  unsigned short* Wvb  = (unsigned short*)(ws + 163840);     // 131072 B
  unsigned short* Q    = (unsigned short*)(ws + 294912);     // 2 MB
  unsigned short* K    = (unsigned short*)(ws + 2392064);    // 2 MB
  unsigned short* V    = (unsigned short*)(ws + 4489216);    // 16 MB
  unsigned short* attn = (unsigned short*)(ws + 21266432);   // 16 MB (end ~38 MB)

  // allow 80 KiB dynamic LDS (gfx950 supports 160 KiB/WG)
  (void)hipFuncSetAttribute((const void*)attn_kernel,
                            hipFuncAttributeMaxDynamicSharedMemorySize, 81920);

  prep_kernel<<<320, 256, 0, stream>>>(Wf, Wg, Wh, Wv, Wall, Wvb);
  proj_kernel<<<512, 256, 0, stream>>>(x, Wall, bfb, bgb, bhb, Q, K, V);
  attn_kernel<<<512, 256, 81920, stream>>>(Q, K, V, attn);
  vproj_kernel<<<512, 256, 0, stream>>>(attn, Wvb, bv, x, gam, out);
}